// Round 1
// 623.248 us; speedup vs baseline: 1.0102x; 1.0102x over previous
//
#include <hip/hip_runtime.h>

// MoE grouped GEMM: out[t, :] = inputs[t, :] @ kernel[expert(t)] + bias[expert(t)]
// E=8, T=8192, I=2048, O=4096. Groups are 1024 each.
//
// R4 -> R5 changes:
//  * moe_gemm: 128^2 4-wave 2-barrier  ->  256^2 8-wave double-buffered 4-phase
//    schedule (T3/T4/T5). Per K-tile: 4 x {ds_read quad + prefetch-issue ->
//    s_barrier -> setprio(1) 16xMFMA setprio(0) -> s_barrier}; ONE
//    __syncthreads() at the tile boundary (drains exactly the 8 next-tile
//    global_load_lds in flight -- counted-vmcnt semantics by construction).
//    Bytes/FLOP halves: 64 KB LDS per 8.4 MFLOP vs 32 KB per 2.1 MFLOP.
//  * XCD queue: 64 tiles/XCD == exactly one expert; A panel (4 MB bf16) = one
//    XCD's L2. idx&3 = row tile (4 consecutive claims share a 1 MB B strip).
//  * XOR k-chunk swizzle kept verbatim (BK=64, conflicts were 0 -- keep).
//  * cvt_a: lane-contiguous float4 -> ushort4 (perfect coalescing both sides)
//    and folds qcnt zeroing (drops the hipMemsetAsync graph node).
//  * cvt_b unchanged (risk isolation; if it shows up in top-5 next, attack it).

typedef short bf16x8 __attribute__((ext_vector_type(8)));      // 8 bf16 (4 VGPRs)
typedef float f32x4 __attribute__((ext_vector_type(4)));       // MFMA acc
typedef unsigned short u16x4 __attribute__((ext_vector_type(4)));
typedef unsigned short u16x8 __attribute__((ext_vector_type(8)));

constexpr int Ecnt = 8;
constexpr int Ttok = 8192;
constexpr int Ifeat = 2048;
constexpr int Ofeat = 4096;

constexpr int BM = 256, BN = 256, BK = 64;
constexpr int NKT = Ifeat / BK;          // 32 K-tiles
constexpr int RTE = (Ttok / Ecnt) / BM;  // 4 row tiles per expert
constexpr int CTN = Ofeat / BN;          // 16 col tiles
constexpr int NTILE = Ecnt * RTE * CTN;  // 512 blocks
constexpr int QCAP = NTILE / 8;          // 64 tiles per XCD queue = 1 expert

__device__ __forceinline__ unsigned short f2bf(float f) {
  unsigned u = __float_as_uint(f);
  unsigned r = (u + 0x7FFFu + ((u >> 16) & 1u)) >> 16;
  return (unsigned short)r;
}

// ---- pre-pass 1: A (T x I) fp32 -> bf16, same layout; zeroes qcnt ----
__global__ __launch_bounds__(256) void cvt_a(const float* __restrict__ src,
                                             unsigned short* __restrict__ dst,
                                             int* __restrict__ qcnt) {
  size_t i = ((size_t)blockIdx.x * 256 + threadIdx.x) * 4;
  float4 f = *(const float4*)(src + i);   // 16 B/lane, lane-contiguous
  u16x4 v;
  v[0] = f2bf(f.x); v[1] = f2bf(f.y); v[2] = f2bf(f.z); v[3] = f2bf(f.w);
  *(u16x4*)(dst + i) = v;                 // 8 B/lane, lane-contiguous
  if (blockIdx.x == 0 && threadIdx.x < 8) qcnt[threadIdx.x] = 0;
}

// ---- pre-pass 2: B (E, I, O) fp32 -> (E, O, I) bf16, transposed ----
__global__ __launch_bounds__(256) void cvt_b(const float* __restrict__ src,
                                             unsigned short* __restrict__ dst) {
  constexpr int LDST = 129;
  __shared__ float tile[64 * LDST];  // 32.25 KB
  const int e = blockIdx.z;
  const int i0 = blockIdx.y * 64;
  const int o0 = blockIdx.x * 128;
  const int tid = threadIdx.x;
  {
    const int tx = tid & 31, ty = tid >> 5;
    const float* s = src + ((size_t)e * Ifeat + i0) * Ofeat + o0 + tx * 4;
#pragma unroll
    for (int r = 0; r < 8; ++r) {
      int i = r * 8 + ty;
      float4 f = *(const float4*)(s + (size_t)i * Ofeat);
      float* l = tile + i * LDST + tx * 4;
      l[0] = f.x; l[1] = f.y; l[2] = f.z; l[3] = f.w;
    }
  }
  __syncthreads();
  {
    const int ic = (tid & 7) * 8;
    const int oc = tid >> 3;
#pragma unroll
    for (int p = 0; p < 4; ++p) {
      int o = p * 32 + oc;
      u16x8 v;
#pragma unroll
      for (int j = 0; j < 8; ++j) v[j] = f2bf(tile[(ic + j) * LDST + o]);
      unsigned short* d =
          dst + ((size_t)e * Ofeat + o0 + o) * Ifeat + i0 + ic;
      *(u16x8*)d = v;
    }
  }
}

// ---- async 16B global -> LDS ----
__device__ __forceinline__ void ld16(const unsigned short* g, unsigned short* l) {
  __builtin_amdgcn_global_load_lds(
      (const __attribute__((address_space(1))) unsigned int*)g,
      (__attribute__((address_space(3))) unsigned int*)l, 16, 0, 0);
}

// ---- main grouped GEMM: 256x256 tile, 8 waves (2M x 4N), dbuf 4-phase ----
__global__ __launch_bounds__(512, 2) void moe_gemm(
    const unsigned short* __restrict__ A,   // T x I bf16
    const unsigned short* __restrict__ Bt,  // E x O x I bf16
    const int* __restrict__ gs,             // E group sizes
    const float* __restrict__ bias,         // E x O fp32
    float* __restrict__ C,                  // T x O fp32
    int* __restrict__ qcnt) {               // 8 per-XCD ticket counters (zeroed)
  __shared__ unsigned short lA[2][BM * BK];  // 2 x 32 KB
  __shared__ unsigned short lB[2][BN * BK];  // 2 x 32 KB  (128 KB total)
  __shared__ int s_tile;

  const int tid = threadIdx.x;

  // --- claim a tile from this XCD's queue (device-scope atomics) ---
  if (tid == 0) {
    // HW_REG_XCC_ID = hwreg id 20; GETREG_IMMED(31,0,20) = 63508.
    unsigned xcc = __builtin_amdgcn_s_getreg(63508) & 7;
    int t = 0;
#pragma unroll
    for (int a = 0; a < 8; ++a) {
      int qq = (xcc + a) & 7;
      int ix = atomicAdd(&qcnt[qq], 1);  // device-scope: cross-XCD coherent
      if (ix < QCAP) { t = (qq << 6) | ix; break; }
      // cannot fail all 8 queues: total capacity == #blocks
    }
    s_tile = t;
  }
  __syncthreads();

  const int tcode = s_tile;
  const int q = tcode >> 6;          // queue == expert
  const int idx = tcode & 63;
  const int rt = idx & (RTE - 1);    // row tile fastest (B-strip reuse x4)
  const int ct = idx >> 2;           // col tile
  const int row0 = q * (Ttok / Ecnt) + rt * BM;
  const int col0 = ct * BN;

  // expert for this row block (groups 128-aligned in this bench)
  int e = 0;
  {
    int cum = 0;
#pragma unroll
    for (int g = 0; g < Ecnt; ++g) {
      int s = gs[g];
      if (row0 >= cum + s) { cum += s; e = g + 1; }
    }
  }

  const unsigned short* __restrict__ Ag = A + (size_t)row0 * Ifeat;
  const unsigned short* __restrict__ Bg = Bt + ((size_t)e * Ofeat + col0) * Ifeat;

  // staging: 2048 16B chunks per matrix, 4 per thread. Physical chunk
  // (r, kcp) holds logical k-chunk kcp ^ (r&7) (XOR swizzle): LDS dest is
  // linear (global_load_lds requirement), source address pre-swizzled.
  int64_t goff[4];
  int lof[4];
#pragma unroll
  for (int p = 0; p < 4; ++p) {
    const int c = tid + p * 512;
    const int r = c >> 3, kcp = c & 7;
    goff[p] = (int64_t)r * Ifeat + ((kcp ^ (r & 7)) << 3);
    lof[p] = c << 3;  // shorts
  }

  const int wave = tid >> 6, lane = tid & 63;
  const int wr = wave >> 2, wc = wave & 3;   // 2 x 4 wave grid
  const int lrow = lane & 15;                // m (A) / n (B) within 16-tile
  const int kg = lane >> 4;                  // k-group 0..3
  const int xr = lrow & 7;                   // XOR swizzle key (row&7)
  const int aslot0 = (kg ^ xr) << 3;         // k-half 0 chunk (shorts)
  const int aslot1 = ((4 + kg) ^ xr) << 3;   // k-half 1 chunk
  const int arbase = (wr * 128 + lrow) * BK; // + mt*16*BK
  const int brbase = (wc * 64 + lrow) * BK;  // + nt*16*BK

  f32x4 acc[8][4];
#pragma unroll
  for (int i = 0; i < 8; ++i)
#pragma unroll
    for (int jj = 0; jj < 4; ++jj) acc[i][jj] = (f32x4){0.f, 0.f, 0.f, 0.f};

  // prologue: stage tile 0 into buffer 0, full drain
#pragma unroll
  for (int p = 0; p < 4; ++p) ld16(Ag + goff[p], &lA[0][lof[p]]);
#pragma unroll
  for (int p = 0; p < 4; ++p) ld16(Bg + goff[p], &lB[0][lof[p]]);
  __syncthreads();

#define AFRAG(MT, SL) (*(const bf16x8*)(al + arbase + (MT) * (16 * BK) + (SL)))
#define MFMA_QUAD(MT0, MT1)                                                  \
  __builtin_amdgcn_s_barrier();                                              \
  __builtin_amdgcn_s_setprio(1);                                             \
  _Pragma("unroll") for (int nt = 0; nt < 4; ++nt) {                         \
    acc[MT0][nt] = __builtin_amdgcn_mfma_f32_16x16x32_bf16(                  \
        a00, bf[nt][0], acc[MT0][nt], 0, 0, 0);                              \
    acc[MT0][nt] = __builtin_amdgcn_mfma_f32_16x16x32_bf16(                  \
        a01, bf[nt][1], acc[MT0][nt], 0, 0, 0);                              \
    acc[MT1][nt] = __builtin_amdgcn_mfma_f32_16x16x32_bf16(                  \
        a10, bf[nt][0], acc[MT1][nt], 0, 0, 0);                              \
    acc[MT1][nt] = __builtin_amdgcn_mfma_f32_16x16x32_bf16(                  \
        a11, bf[nt][1], acc[MT1][nt], 0, 0, 0);                              \
  }                                                                          \
  __builtin_amdgcn_s_setprio(0);

  int cur = 0;
  for (int kt = 0; kt < NKT; ++kt) {
    const unsigned short* al = lA[cur];
    const unsigned short* bl = lB[cur];
    unsigned short* an = lA[cur ^ 1];
    unsigned short* bn = lB[cur ^ 1];
    const int64_t kn = (int64_t)(kt + 1) * BK;
    const bool pf = (kt + 1 < NKT);

    // B fragments for the whole K-tile (reused by all 4 phases): 8 x b128
    bf16x8 bf[4][2];
#pragma unroll
    for (int nt = 0; nt < 4; ++nt) {
      bf[nt][0] = *(const bf16x8*)(bl + brbase + nt * (16 * BK) + aslot0);
      bf[nt][1] = *(const bf16x8*)(bl + brbase + nt * (16 * BK) + aslot1);
    }

    // ---- phase 0: mt {0,1}; issue next-tile A stage (4 x ld16) ----
    {
      bf16x8 a00 = AFRAG(0, aslot0), a01 = AFRAG(0, aslot1);
      bf16x8 a10 = AFRAG(1, aslot0), a11 = AFRAG(1, aslot1);
      if (pf) {
        ld16(Ag + goff[0] + kn, an + lof[0]);
        ld16(Ag + goff[1] + kn, an + lof[1]);
        ld16(Ag + goff[2] + kn, an + lof[2]);
        ld16(Ag + goff[3] + kn, an + lof[3]);
      }
      MFMA_QUAD(0, 1)
      __builtin_amdgcn_s_barrier();
    }
    // ---- phase 1: mt {2,3}; issue next-tile B stage (4 x ld16) ----
    {
      bf16x8 a00 = AFRAG(2, aslot0), a01 = AFRAG(2, aslot1);
      bf16x8 a10 = AFRAG(3, aslot0), a11 = AFRAG(3, aslot1);
      if (pf) {
        ld16(Bg + goff[0] + kn, bn + lof[0]);
        ld16(Bg + goff[1] + kn, bn + lof[1]);
        ld16(Bg + goff[2] + kn, bn + lof[2]);
        ld16(Bg + goff[3] + kn, bn + lof[3]);
      }
      MFMA_QUAD(2, 3)
      __builtin_amdgcn_s_barrier();
    }
    // ---- phase 2: mt {4,5} ----
    {
      bf16x8 a00 = AFRAG(4, aslot0), a01 = AFRAG(4, aslot1);
      bf16x8 a10 = AFRAG(5, aslot0), a11 = AFRAG(5, aslot1);
      MFMA_QUAD(4, 5)
      __builtin_amdgcn_s_barrier();
    }
    // ---- phase 3: mt {6,7}; boundary ----
    {
      bf16x8 a00 = AFRAG(6, aslot0), a01 = AFRAG(6, aslot1);
      bf16x8 a10 = AFRAG(7, aslot0), a11 = AFRAG(7, aslot1);
      MFMA_QUAD(6, 7)
    }
    // boundary: drains this thread's 8 in-flight global_load_lds (the next
    // tile -- exactly what phase 0 needs) + WAR on buf[cur] for all waves.
    __syncthreads();
    cur ^= 1;
  }
#undef AFRAG
#undef MFMA_QUAD

  // epilogue: C/D layout col = lane&15, row = (lane>>4)*4 + reg  [m89]
  const int r0 = (lane >> 4) * 4;
  const int cc = lane & 15;
  const float* be = bias + (size_t)e * Ofeat;
#pragma unroll
  for (int mt = 0; mt < 8; ++mt) {
    const int row = row0 + wr * 128 + mt * 16 + r0;
#pragma unroll
    for (int nt = 0; nt < 4; ++nt) {
      const int col = col0 + wc * 64 + nt * 16 + cc;
      const float b = be[col];
      float* Cp = C + (size_t)row * Ofeat + col;
#pragma unroll
      for (int r = 0; r < 4; ++r) Cp[(size_t)r * Ofeat] = acc[mt][nt][r] + b;
    }
  }
}

extern "C" void kernel_launch(void* const* d_in, const int* in_sizes, int n_in,
                              void* d_out, int out_size, void* d_ws, size_t ws_size,
                              hipStream_t stream) {
  const float* inputs = (const float*)d_in[0];        // T x I
  const int* group_sizes = (const int*)d_in[1];       // E
  const float* kern = (const float*)d_in[2];          // E x I x O
  const float* bias = (const float*)d_in[3];          // E x O
  float* out = (float*)d_out;                         // T x O

  unsigned short* Abf = (unsigned short*)d_ws;                    // T*I bf16
  unsigned short* Bbf = Abf + (size_t)Ttok * Ifeat;               // E*O*I bf16
  const size_t cnt_off = (size_t)Ttok * Ifeat * 2 + (size_t)Ecnt * Ofeat * Ifeat * 2;
  int* qcnt = (int*)((char*)d_ws + cnt_off);                      // 8 ints

  cvt_a<<<(Ttok * (size_t)Ifeat) / (4 * 256), 256, 0, stream>>>(inputs, Abf, qcnt);
  cvt_b<<<dim3(Ofeat / 128, Ifeat / 64, Ecnt), 256, 0, stream>>>(kern, Bbf);

  moe_gemm<<<NTILE, 512, 0, stream>>>(Abf, Bbf, group_sizes, bias, out, qcnt);
}

// Round 3
// 615.217 us; speedup vs baseline: 1.0234x; 1.0131x over previous
//
#include <hip/hip_runtime.h>

// MoE grouped GEMM: out[t, :] = inputs[t, :] @ kernel[expert(t)] + bias[expert(t)]
// E=8, T=8192, I=2048, O=4096. Groups are 1024 each.
//
// R7 == R6 resubmission (R6 bench died with a container-level infra error,
// never measured; audit found no hang path -- see journal).
//
// R5 -> R6 changes (post-mortem: R5 == R4 because the per-tile __syncthreads
// is a vmcnt(0) drain; with a 2-deep dbuf the prefetch distance is 1 so the
// drain is structural. m218: counted-vs-drain0 IS the 8-phase gain):
//  * BK 64 -> 32, LDS = 4-deep circular buffer (4 x (16KB A + 16KB B) = 128KB),
//    prefetch distance 3. Boundary wait is s_waitcnt vmcnt(8) (+ tail 4/0),
//    NEVER a full drain in the main loop. Wait-then-barrier ordering: each
//    wave certifies ITS OWN next-tile loads landed before the barrier, so
//    after the barrier all waves' data is in (per-wave vmcnt is not a
//    cross-wave guarantee without this ordering).
//  * Paired-row XOR swizzle for BK=32 (64B rows): 128B line = rows {2l,2l+1},
//    physical seg = (((r&1)<<2)|kc) ^ (l&7). Same 2-lanes-per-16B-segment
//    bank profile as the proven BK=64 swizzle. Staging source pre-swizzled,
//    LDS dest linear (global_load_lds requirement).
//  * Per tile: 2 phases x {ds_read 8/4 x b128 + 2 stage-issue -> s_barrier ->
//    lgkmcnt(0)+sched_barrier -> setprio(1) 16 MFMA setprio(0) -> s_barrier}.
//    All 16 MFMAs per phase independent (no acc chains at BK=32).
//  * XCD ticket queue, cvt_a, cvt_b unchanged.

typedef short bf16x8 __attribute__((ext_vector_type(8)));      // 8 bf16 (4 VGPRs)
typedef float f32x4 __attribute__((ext_vector_type(4)));       // MFMA acc
typedef unsigned short u16x4 __attribute__((ext_vector_type(4)));
typedef unsigned short u16x8 __attribute__((ext_vector_type(8)));

constexpr int Ecnt = 8;
constexpr int Ttok = 8192;
constexpr int Ifeat = 2048;
constexpr int Ofeat = 4096;

constexpr int BM = 256, BN = 256, BK = 32;
constexpr int NKT = Ifeat / BK;          // 64 K-tiles
constexpr int NBUF = 4;                  // circular buffer depth
constexpr int RTE = (Ttok / Ecnt) / BM;  // 4 row tiles per expert
constexpr int CTN = Ofeat / BN;          // 16 col tiles
constexpr int NTILE = Ecnt * RTE * CTN;  // 512 blocks
constexpr int QCAP = NTILE / 8;          // 64 tiles per XCD queue = 1 expert

__device__ __forceinline__ unsigned short f2bf(float f) {
  unsigned u = __float_as_uint(f);
  unsigned r = (u + 0x7FFFu + ((u >> 16) & 1u)) >> 16;
  return (unsigned short)r;
}

// ---- pre-pass 1: A (T x I) fp32 -> bf16, same layout; zeroes qcnt ----
__global__ __launch_bounds__(256) void cvt_a(const float* __restrict__ src,
                                             unsigned short* __restrict__ dst,
                                             int* __restrict__ qcnt) {
  size_t i = ((size_t)blockIdx.x * 256 + threadIdx.x) * 4;
  float4 f = *(const float4*)(src + i);   // 16 B/lane, lane-contiguous
  u16x4 v;
  v[0] = f2bf(f.x); v[1] = f2bf(f.y); v[2] = f2bf(f.z); v[3] = f2bf(f.w);
  *(u16x4*)(dst + i) = v;                 // 8 B/lane, lane-contiguous
  if (blockIdx.x == 0 && threadIdx.x < 8) qcnt[threadIdx.x] = 0;
}

// ---- pre-pass 2: B (E, I, O) fp32 -> (E, O, I) bf16, transposed ----
__global__ __launch_bounds__(256) void cvt_b(const float* __restrict__ src,
                                             unsigned short* __restrict__ dst) {
  constexpr int LDST = 129;
  __shared__ float tile[64 * LDST];  // 32.25 KB
  const int e = blockIdx.z;
  const int i0 = blockIdx.y * 64;
  const int o0 = blockIdx.x * 128;
  const int tid = threadIdx.x;
  {
    const int tx = tid & 31, ty = tid >> 5;
    const float* s = src + ((size_t)e * Ifeat + i0) * Ofeat + o0 + tx * 4;
#pragma unroll
    for (int r = 0; r < 8; ++r) {
      int i = r * 8 + ty;
      float4 f = *(const float4*)(s + (size_t)i * Ofeat);
      float* l = tile + i * LDST + tx * 4;
      l[0] = f.x; l[1] = f.y; l[2] = f.z; l[3] = f.w;
    }
  }
  __syncthreads();
  {
    const int ic = (tid & 7) * 8;
    const int oc = tid >> 3;
#pragma unroll
    for (int p = 0; p < 4; ++p) {
      int o = p * 32 + oc;
      u16x8 v;
#pragma unroll
      for (int j = 0; j < 8; ++j) v[j] = f2bf(tile[(ic + j) * LDST + o]);
      unsigned short* d =
          dst + ((size_t)e * Ofeat + o0 + o) * Ifeat + i0 + ic;
      *(u16x8*)d = v;
    }
  }
}

// ---- async 16B global -> LDS ----
__device__ __forceinline__ void ld16(const unsigned short* g, unsigned short* l) {
  __builtin_amdgcn_global_load_lds(
      (const __attribute__((address_space(1))) unsigned int*)g,
      (__attribute__((address_space(3))) unsigned int*)l, 16, 0, 0);
}

// ---- main grouped GEMM: 256x256, 8 waves, 4-deep pipeline, counted vmcnt ----
__global__ __launch_bounds__(512, 2) void moe_gemm(
    const unsigned short* __restrict__ A,   // T x I bf16
    const unsigned short* __restrict__ Bt,  // E x O x I bf16
    const int* __restrict__ gs,             // E group sizes
    const float* __restrict__ bias,         // E x O fp32
    float* __restrict__ C,                  // T x O fp32
    int* __restrict__ qcnt) {               // 8 per-XCD ticket counters (zeroed)
  __shared__ unsigned short lA[NBUF][BM * BK];  // 4 x 16 KB
  __shared__ unsigned short lB[NBUF][BN * BK];  // 4 x 16 KB  (128 KB total)
  __shared__ int s_tile;

  const int tid = threadIdx.x;

  // --- claim a tile from this XCD's queue (device-scope atomics) ---
  if (tid == 0) {
    // HW_REG_XCC_ID = hwreg id 20; GETREG_IMMED(31,0,20) = 63508.
    unsigned xcc = __builtin_amdgcn_s_getreg(63508) & 7;
    int t = 0;
#pragma unroll
    for (int a = 0; a < 8; ++a) {
      int qq = (xcc + a) & 7;
      int ix = atomicAdd(&qcnt[qq], 1);  // device-scope: cross-XCD coherent
      if (ix < QCAP) { t = (qq << 6) | ix; break; }
      // cannot fail all 8 queues: total capacity == #blocks
    }
    s_tile = t;
  }
  __syncthreads();

  const int tcode = s_tile;
  const int q = tcode >> 6;          // queue == expert
  const int idx = tcode & 63;
  const int rt = idx & (RTE - 1);    // row tile fastest (B-strip reuse x4)
  const int ct = idx >> 2;           // col tile
  const int row0 = q * (Ttok / Ecnt) + rt * BM;
  const int col0 = ct * BN;

  // expert for this row block (groups 128-aligned in this bench)
  int e = 0;
  {
    int cum = 0;
#pragma unroll
    for (int g = 0; g < Ecnt; ++g) {
      int s = gs[g];
      if (row0 >= cum + s) { cum += s; e = g + 1; }
    }
  }

  const unsigned short* __restrict__ Ag = A + (size_t)row0 * Ifeat;
  const unsigned short* __restrict__ Bg = Bt + ((size_t)e * Ofeat + col0) * Ifeat;

  // ---- staging map (per thread, 2 chunks per matrix per K-tile) ----
  // Physical chunk f (16B) = line l = f>>3 (128B, rows {2l, 2l+1}), seg = f&7.
  // Logical seg = seg ^ (l&7); logical row r = 2l + (lseg>>2); kc = lseg&3.
  // Global source (shorts) = r*Ifeat + kt*32 + kc*8. LDS dest linear = f*16B.
  int64_t soff[2];
  int lof[2];
#pragma unroll
  for (int p = 0; p < 2; ++p) {
    const int f = tid + p * 512;
    const int l = f >> 3;
    const int ls = (f & 7) ^ (l & 7);
    const int r = 2 * l + (ls >> 2);
    const int kc = ls & 3;
    soff[p] = (int64_t)r * Ifeat + kc * 8;
    lof[p] = f * 8;  // shorts
  }

  const int wave = tid >> 6, lane = tid & 63;
  const int wr = wave >> 2, wc = wave & 3;   // 2 x 4 wave grid
  const int lrow = lane & 15;                // m (A) / n (B) within 16-tile
  const int kg = lane >> 4;                  // k-group 0..3 (8 elems each)

  // frag read offset (shorts) for tile-row R, k-group kg (paired-row swizzle)
  auto frd = [&](int R) {
    return (R >> 1) * 64 + (((((R & 1) << 2) | kg) ^ ((R >> 1) & 7)) << 3);
  };
  int aoff[8], boff[4];
#pragma unroll
  for (int mt = 0; mt < 8; ++mt) aoff[mt] = frd(wr * 128 + mt * 16 + lrow);
#pragma unroll
  for (int nt = 0; nt < 4; ++nt) boff[nt] = frd(wc * 64 + nt * 16 + lrow);

  f32x4 acc[8][4];
#pragma unroll
  for (int i = 0; i < 8; ++i)
#pragma unroll
    for (int jj = 0; jj < 4; ++jj) acc[i][jj] = (f32x4){0.f, 0.f, 0.f, 0.f};

#define STAGE_A(BUF, KT)                                      \
  ld16(Ag + soff[0] + (int64_t)(KT) * BK, &lA[BUF][lof[0]]);  \
  ld16(Ag + soff[1] + (int64_t)(KT) * BK, &lA[BUF][lof[1]]);
#define STAGE_B(BUF, KT)                                      \
  ld16(Bg + soff[0] + (int64_t)(KT) * BK, &lB[BUF][lof[0]]);  \
  ld16(Bg + soff[1] + (int64_t)(KT) * BK, &lB[BUF][lof[1]]);

  // prologue: stage tiles 0,1,2 (12 loads in flight)
  STAGE_A(0, 0) STAGE_B(0, 0)
  STAGE_A(1, 1) STAGE_B(1, 1)
  STAGE_A(2, 2) STAGE_B(2, 2)
  // boundary into tile 0: own stage(0) landed (8 newer = stages 1,2 in flight)
  asm volatile("s_waitcnt vmcnt(8)" ::: "memory");
  __builtin_amdgcn_s_barrier();
  __builtin_amdgcn_sched_barrier(0);

  for (int t = 0; t < NKT; ++t) {
    const unsigned short* la = &lA[t & 3][0];
    const unsigned short* lb = &lB[t & 3][0];
    const bool pf = (t + 3 < NKT);
    const int nb = (t + 3) & 3;

    // B fragments for the whole K-tile
    bf16x8 bq[4];
#pragma unroll
    for (int nt = 0; nt < 4; ++nt) bq[nt] = *(const bf16x8*)(lb + boff[nt]);

    // ---- phase A: mt 0..3; issue next A stage ----
    {
      bf16x8 aq[4];
#pragma unroll
      for (int mt = 0; mt < 4; ++mt) aq[mt] = *(const bf16x8*)(la + aoff[mt]);
      if (pf) { STAGE_A(nb, t + 3) }
      __builtin_amdgcn_s_barrier();
      asm volatile("s_waitcnt lgkmcnt(0)" ::: "memory");
      __builtin_amdgcn_sched_barrier(0);
      __builtin_amdgcn_s_setprio(1);
#pragma unroll
      for (int mt = 0; mt < 4; ++mt)
#pragma unroll
        for (int nt = 0; nt < 4; ++nt)
          acc[mt][nt] = __builtin_amdgcn_mfma_f32_16x16x32_bf16(
              aq[mt], bq[nt], acc[mt][nt], 0, 0, 0);
      __builtin_amdgcn_s_setprio(0);
      __builtin_amdgcn_s_barrier();
    }
    // ---- phase B: mt 4..7; issue next B stage ----
    {
      bf16x8 aq[4];
#pragma unroll
      for (int mt = 0; mt < 4; ++mt)
        aq[mt] = *(const bf16x8*)(la + aoff[4 + mt]);
      if (pf) { STAGE_B(nb, t + 3) }
      __builtin_amdgcn_s_barrier();
      asm volatile("s_waitcnt lgkmcnt(0)" ::: "memory");
      __builtin_amdgcn_sched_barrier(0);
      __builtin_amdgcn_s_setprio(1);
#pragma unroll
      for (int mt = 0; mt < 4; ++mt)
#pragma unroll
        for (int nt = 0; nt < 4; ++nt)
          acc[4 + mt][nt] = __builtin_amdgcn_mfma_f32_16x16x32_bf16(
              aq[mt], bq[nt], acc[4 + mt][nt], 0, 0, 0);
      __builtin_amdgcn_s_setprio(0);
    }

    // ---- boundary: certify OWN stage(t+1) landed, then barrier ----
    // Outstanding newer loads: stages t+2, t+3 (4 each, if they exist).
    if (t < NKT - 1) {
      if (t < NKT - 3) {
        asm volatile("s_waitcnt vmcnt(8)" ::: "memory");
      } else if (t == NKT - 3) {
        asm volatile("s_waitcnt vmcnt(4)" ::: "memory");
      } else {
        asm volatile("s_waitcnt vmcnt(0)" ::: "memory");
      }
      __builtin_amdgcn_s_barrier();
      __builtin_amdgcn_sched_barrier(0);
    }
  }
#undef STAGE_A
#undef STAGE_B

  // epilogue: C/D layout col = lane&15, row = (lane>>4)*4 + reg  [m89]
  const int r0 = (lane >> 4) * 4;
  const int cc = lane & 15;
  const float* be = bias + (size_t)e * Ofeat;
#pragma unroll
  for (int mt = 0; mt < 8; ++mt) {
    const int row = row0 + wr * 128 + mt * 16 + r0;
#pragma unroll
    for (int nt = 0; nt < 4; ++nt) {
      const int col = col0 + wc * 64 + nt * 16 + cc;
      const float b = be[col];
      float* Cp = C + (size_t)row * Ofeat + col;
#pragma unroll
      for (int r = 0; r < 4; ++r) Cp[(size_t)r * Ofeat] = acc[mt][nt][r] + b;
    }
  }
}

extern "C" void kernel_launch(void* const* d_in, const int* in_sizes, int n_in,
                              void* d_out, int out_size, void* d_ws, size_t ws_size,
                              hipStream_t stream) {
  const float* inputs = (const float*)d_in[0];        // T x I
  const int* group_sizes = (const int*)d_in[1];       // E
  const float* kern = (const float*)d_in[2];          // E x I x O
  const float* bias = (const float*)d_in[3];          // E x O
  float* out = (float*)d_out;                         // T x O

  unsigned short* Abf = (unsigned short*)d_ws;                    // T*I bf16
  unsigned short* Bbf = Abf + (size_t)Ttok * Ifeat;               // E*O*I bf16
  const size_t cnt_off = (size_t)Ttok * Ifeat * 2 + (size_t)Ecnt * Ofeat * Ifeat * 2;
  int* qcnt = (int*)((char*)d_ws + cnt_off);                      // 8 ints

  cvt_a<<<(Ttok * (size_t)Ifeat) / (4 * 256), 256, 0, stream>>>(inputs, Abf, qcnt);
  cvt_b<<<dim3(Ofeat / 128, Ifeat / 64, Ecnt), 256, 0, stream>>>(kern, Bbf);

  moe_gemm<<<NTILE, 512, 0, stream>>>(Abf, Bbf, group_sizes, bias, out, qcnt);
}